// Round 5
// baseline (115.282 us; speedup 1.0000x reference)
//
#include <hip/hip_runtime.h>
#include <math.h>

#define DIM 4096     // D: 12 FWHT stages
#define ROWS 2048    // B
#define LSTR 68      // transpose stride (64+4): 16B-aligned lane rows -> b128
                     // writes; read bank (4m+lane)%32 -> 2-way = free (m136)

// g LDS image: Lg[e + (e>>6)] (pad 1 word per 64) -> layout-B read is 2-way.
#define GPAD(e) ((e) + ((e) >> 6))
#define GSZ (DIM + DIM / 64)   // 4160 floats

__device__ __forceinline__ float4 f4mul(float4 a, float4 b) {
    return make_float4(a.x * b.x, a.y * b.y, a.z * b.z, a.w * b.w);
}

// 6 stages over bits i = e[0:2) (inside float4) and r = e[8:12) (across regs).
__device__ __forceinline__ void fwht_ri(float4 v[16]) {
#pragma unroll
    for (int j = 0; j < 16; ++j) {
        float4 a = v[j];
        float t0 = a.x + a.y, t1 = a.x - a.y;
        float t2 = a.z + a.w, t3 = a.z - a.w;
        v[j] = make_float4(t0 + t2, t1 + t3, t0 - t2, t1 - t3);
    }
#pragma unroll
    for (int m = 1; m < 16; m <<= 1) {
#pragma unroll
        for (int j = 0; j < 16; ++j) {
            if (!(j & m)) {
                int k = j | m;
                float4 a = v[j], b = v[k];
                v[j] = make_float4(a.x + b.x, a.y + b.y, a.z + b.z, a.w + b.w);
                v[k] = make_float4(a.x - b.x, a.y - b.y, a.z - b.z, a.w - b.w);
            }
        }
    }
}

// 6 stages over bits m = e[2:8) (in-register after the transpose).
__device__ __forceinline__ void fwht_m(float f[64]) {
#pragma unroll
    for (int s = 0; s < 6; ++s) {
        const int h = 1 << s;
#pragma unroll
        for (int m = 0; m < 64; ++m) {
            if (!(m & h)) {
                const int k = m | h;
                float a = f[m], b = f[k];
                f[m] = a + b;
                f[k] = a - b;
            }
        }
    }
}

// One wave per row: out = s1 * FWHT( g * FWHT( s2 * x_row ) ), fully fused.
// g = g_mu + softplus(g_rho)*eps computed ONCE per block (cooperative, LDS).
// Layout A: lane l, slot c=4r+i -> e = 256r + 4l + i   (coalesced b128 I/O)
// Layout B: lane l, slot m      -> e = 256(l>>2) + 4m + (l&3)
__global__ void __launch_bounds__(128)
whvi_main(const float* __restrict__ x, const float* __restrict__ s1,
          const float* __restrict__ s2, const float* __restrict__ eps,
          const float* __restrict__ g_mu, const float* __restrict__ g_rho,
          float* __restrict__ out) {
    const int lane = threadIdx.x & 63;
    const int wid  = threadIdx.x >> 6;                 // 0..1
    const int row  = blockIdx.x * 2 + wid;             // 1024 blocks x 2 waves

    // 2 x 17.4 KB transpose (wave-private) + 16.6 KB g  = 51.4 KB -> 3 blk/CU
    __shared__ float lds[2 * 64 * LSTR];
    __shared__ float Lg[GSZ];
    float* __restrict__ L  = lds + wid * 64 * LSTR;
    float4* __restrict__ L4 = (float4*)L;              // 16B-aligned lane rows

    const float4* __restrict__ xr  = (const float4*)(x + (size_t)row * DIM);
    float4* __restrict__       orw = (float4*)(out + (size_t)row * DIM);
    const float4* __restrict__ s2v = (const float4*)s2;
    const float4* __restrict__ s1v = (const float4*)s1;

    float f[64];
    float4* F = (float4*)f;

    // ---- issue row loads FIRST: 32 b128 loads in flight during g-fill
#pragma unroll
    for (int r = 0; r < 16; ++r)
        F[r] = f4mul(xr[64 * r + lane], s2v[64 * r + lane]);

    // ---- cooperative g fill: 8 float4 x 3 arrays per thread, coalesced.
    {
        const float4* __restrict__ e4 = (const float4*)eps;
        const float4* __restrict__ m4 = (const float4*)g_mu;
        const float4* __restrict__ r4 = (const float4*)g_rho;
#pragma unroll
        for (int k = 0; k < 8; ++k) {
            const int fi = threadIdx.x + 128 * k;      // float4 index 0..1023
            const int e0 = 4 * fi;
            float4 ev = e4[fi], mv = m4[fi], rv = r4[fi];
            const int w0 = GPAD(e0);                   // e0..e0+3 share (e>>6)
            Lg[w0 + 0] = fmaf(log1pf(expf(rv.x)), ev.x, mv.x);
            Lg[w0 + 1] = fmaf(log1pf(expf(rv.y)), ev.y, mv.y);
            Lg[w0 + 2] = fmaf(log1pf(expf(rv.z)), ev.z, mv.z);
            Lg[w0 + 3] = fmaf(log1pf(expf(rv.w)), ev.w, mv.w);
        }
    }
    __syncthreads();   // Lg ready (transpose regions stay wave-private)

    // ---- FWHT1: (i,r) stages
    fwht_ri(F);

    // ---- transpose A->B: 16 ds_write_b128 + 64 ds_read_b32 (2-way = free)
#pragma unroll
    for (int r = 0; r < 16; ++r)
        L4[lane * (LSTR / 4) + r] = F[r];
#pragma unroll
    for (int m = 0; m < 64; ++m)
        f[m] = L[m * LSTR + lane];

    // ---- FWHT1: m stages (completes FWHT1)
    fwht_m(f);

    // ---- g multiply from LDS image (layout B; pad -> 2-way = free)
    {
        const int base = 256 * (lane >> 2) + (lane & 3);
#pragma unroll
        for (int m = 0; m < 64; ++m) {
            const int e = base + 4 * m;
            f[m] *= Lg[GPAD(e)];
        }
    }

    // ---- FWHT2: m stages
    fwht_m(f);

    // ---- transpose B->A: 16 ds_write_b128 + 64 ds_read_b32
#pragma unroll
    for (int k = 0; k < 16; ++k)
        L4[lane * (LSTR / 4) + k] = F[k];
#pragma unroll
    for (int c = 0; c < 64; ++c)
        f[c] = L[c * LSTR + lane];

    // ---- FWHT2: (i,r) stages (completes FWHT2)
    fwht_ri(F);

    // ---- s1 scale + coalesced store (layout A)
#pragma unroll
    for (int r = 0; r < 16; ++r)
        orw[64 * r + lane] = f4mul(F[r], s1v[64 * r + lane]);
}

extern "C" void kernel_launch(void* const* d_in, const int* in_sizes, int n_in,
                              void* d_out, int out_size, void* d_ws, size_t ws_size,
                              hipStream_t stream) {
    // setup_inputs order: x, epsilon, s1, s2, g_mu, g_rho
    const float* x     = (const float*)d_in[0];
    const float* eps   = (const float*)d_in[1];
    const float* s1    = (const float*)d_in[2];
    const float* s2    = (const float*)d_in[3];
    const float* g_mu  = (const float*)d_in[4];
    const float* g_rho = (const float*)d_in[5];
    float* out = (float*)d_out;

    // Single fused kernel: 2048 rows, 1 wave/row, 2 waves/block.
    whvi_main<<<ROWS / 2, 128, 0, stream>>>(x, s1, s2, eps, g_mu, g_rho, out);
}

// Round 6
// 100.365 us; speedup vs baseline: 1.1486x; 1.1486x over previous
//
#include <hip/hip_runtime.h>
#include <math.h>

#define DIM 4096
#define ROWS 2048
#define SB 68   // LDS image stride in halves: %4==0 -> 8B-aligned half4 writes;
                // b16 frag reads conflict-free (bank = 16(q&1)+2j+8J+(n>>1))

typedef _Float16 half8  __attribute__((ext_vector_type(8)));
typedef _Float16 half4  __attribute__((ext_vector_type(4)));
typedef float    float4e __attribute__((ext_vector_type(4)));

// ---- pre-kernel: g[e] = g_mu + softplus(g_rho) * eps  (plain order, 16 KB)
__global__ void g_precompute(const float* __restrict__ eps,
                             const float* __restrict__ g_mu,
                             const float* __restrict__ g_rho,
                             float* __restrict__ g) {
    int i = blockIdx.x * blockDim.x + threadIdx.x;
    g[i] = fmaf(log1pf(expf(g_rho[i])), eps[i], g_mu[i]);
}

// One "H on the left" GEMM stage: acc(I,J) = sum_Kt H(I,Kt) x B(J,Kt),
// B read from the 64x64 fp16 image (img[a][b], b contiguous, stride SB):
// B[k][n'] = img[k][16J+n], k = 32Kt + 8q + j  (A/B layouts per m89/m120).
__device__ __forceinline__ void hx_stage(const _Float16* __restrict__ img,
                                         int n, int q, const half8 Hf[4][2],
                                         float4e acc[4][4]) {
    half8 B[4][2];
#pragma unroll
    for (int J = 0; J < 4; ++J)
#pragma unroll
        for (int Kt = 0; Kt < 2; ++Kt) {
            const _Float16* p = img + (32 * Kt + 8 * q) * SB + 16 * J + n;
            half8 b;
#pragma unroll
            for (int j = 0; j < 8; ++j) b[j] = p[j * SB];
            B[J][Kt] = b;
        }
#pragma unroll
    for (int I = 0; I < 4; ++I)
#pragma unroll
        for (int J = 0; J < 4; ++J) {
            float4e c = {0.0f, 0.0f, 0.0f, 0.0f};
            c = __builtin_amdgcn_mfma_f32_16x16x32_f16(Hf[I][0], B[J][0], c, 0, 0, 0);
            c = __builtin_amdgcn_mfma_f32_16x16x32_f16(Hf[I][1], B[J][1], c, 0, 0, 0);
            acc[I][J] = c;
        }
}

// Write acc (C-layout: row=16I+4q+r, col=16J+n [m89]) TRANSPOSED to the image:
// img[col][row] -> image = ACC^T. 4 contiguous rows -> one 8B half4 write.
__device__ __forceinline__ void img_write_T(_Float16* __restrict__ img,
                                            int n, int q, const float4e acc[4][4]) {
#pragma unroll
    for (int I = 0; I < 4; ++I)
#pragma unroll
        for (int J = 0; J < 4; ++J) {
            half4 h;
            h[0] = (_Float16)acc[I][J][0];
            h[1] = (_Float16)acc[I][J][1];
            h[2] = (_Float16)acc[I][J][2];
            h[3] = (_Float16)acc[I][J][3];
            *(half4*)(img + (16 * J + n) * SB + 16 * I + 4 * q) = h;
        }
}

// One wave per row. FWHT_4096 = H64 (x) H64: with M[a][b] = v[64a+b],
// FWHT(v) as matrix = H.M.H. Full op out = s1*FWHT(g*FWHT(s2*x)):
//   P = H.M          (img0 = M)
//   Z^T = H.P^T      (img1 = P^T)     Z = H M H  (FWHT1)
//   acc *= g         (g[e], e = 1024J + 64n + 16I + 4q + r  == Z^T element)
//   R = H.Z'         (img2 = Z')
//   Y^T = H.R^T      (img3 = R^T)     Y = H Z' H (FWHT2)
//   out[e] = s1[e] * Y^T element.
// All H-on-the-left: A operand is H fragments, exact +/-1 via popc parity.
__global__ void __launch_bounds__(256, 2)
whvi_mfma(const float* __restrict__ x, const float* __restrict__ s1,
          const float* __restrict__ s2, const float* __restrict__ g,
          float* __restrict__ out) {
    const int lane = threadIdx.x & 63;
    const int wid  = threadIdx.x >> 6;
    const int row  = blockIdx.x * 4 + wid;     // 512 blocks x 4 waves = 2048 rows
    const int n = lane & 15, q = lane >> 4;

    __shared__ __align__(16) _Float16 lds[4 * 64 * SB];   // 34 KB/block
    _Float16* __restrict__ img = lds + wid * 64 * SB;     // wave-private

    const float4e* __restrict__ xr  = (const float4e*)(x + (size_t)row * DIM);
    const float4e* __restrict__ s2v = (const float4e*)s2;

    // ---- issue row loads first (32 b128 in flight)
    float4e xv[16], sv[16];
#pragma unroll
    for (int r = 0; r < 16; ++r) xv[r] = xr[64 * r + lane];
#pragma unroll
    for (int r = 0; r < 16; ++r) sv[r] = s2v[64 * r + lane];

    // ---- H fragments (A-layout: m=lane&15, k=8q+j [m120]); overlaps load latency
    half8 Hf[4][2];
#pragma unroll
    for (int I = 0; I < 4; ++I)
#pragma unroll
        for (int Kt = 0; Kt < 2; ++Kt) {
            half8 h;
#pragma unroll
            for (int j = 0; j < 8; ++j) {
                int rr = 16 * I + n, cc = 32 * Kt + 8 * q + j;
                h[j] = (__popc(rr & cc) & 1) ? (_Float16)(-1.0f) : (_Float16)(1.0f);
            }
            Hf[I][Kt] = h;
        }

    // ---- IMG0 = M = s2*x: element e=256r+4*lane+i -> img[(4r+q)*SB + 4n + i]
#pragma unroll
    for (int r = 0; r < 16; ++r) {
        float4e p = xv[r] * sv[r];
        half4 h;
        h[0] = (_Float16)p[0]; h[1] = (_Float16)p[1];
        h[2] = (_Float16)p[2]; h[3] = (_Float16)p[3];
        *(half4*)(img + (4 * r + q) * SB + 4 * n) = h;
    }

    float4e acc[4][4];

    hx_stage(img, n, q, Hf, acc);        // P = H.M
    img_write_T(img, n, q, acc);         // img = P^T   (in-order DS: safe reuse)
    hx_stage(img, n, q, Hf, acc);        // Z^T

    // ---- g multiply (Z^T element == g[e]); 16 KB array, L1/L2-hot b128 loads
#pragma unroll
    for (int I = 0; I < 4; ++I)
#pragma unroll
        for (int J = 0; J < 4; ++J) {
            const float4e gg = *(const float4e*)(g + 1024 * J + 64 * n + 16 * I + 4 * q);
            acc[I][J] *= gg;
        }

    img_write_T(img, n, q, acc);         // img = Z'
    hx_stage(img, n, q, Hf, acc);        // R = H.Z'
    img_write_T(img, n, q, acc);         // img = R^T
    hx_stage(img, n, q, Hf, acc);        // Y^T

    // ---- s1 scale + store: e = 1024J + 64n + 16I + 4q (+r): b128, line-covered
    float* __restrict__ orow = out + (size_t)row * DIM;
#pragma unroll
    for (int I = 0; I < 4; ++I)
#pragma unroll
        for (int J = 0; J < 4; ++J) {
            const int e = 1024 * J + 64 * n + 16 * I + 4 * q;
            const float4e sg = *(const float4e*)(s1 + e);
            *(float4e*)(orow + e) = acc[I][J] * sg;
        }
}

extern "C" void kernel_launch(void* const* d_in, const int* in_sizes, int n_in,
                              void* d_out, int out_size, void* d_ws, size_t ws_size,
                              hipStream_t stream) {
    // setup_inputs order: x, epsilon, s1, s2, g_mu, g_rho
    const float* x     = (const float*)d_in[0];
    const float* eps   = (const float*)d_in[1];
    const float* s1    = (const float*)d_in[2];
    const float* s2    = (const float*)d_in[3];
    const float* g_mu  = (const float*)d_in[4];
    const float* g_rho = (const float*)d_in[5];
    float* out = (float*)d_out;
    float* g   = (float*)d_ws;   // 4096 floats

    g_precompute<<<DIM / 256, 256, 0, stream>>>(eps, g_mu, g_rho, g);
    whvi_mfma<<<ROWS / 4, 256, 0, stream>>>(x, s1, s2, g, out);
}